// Round 10
// baseline (258.753 us; speedup 1.0000x reference)
//
#include <hip/hip_runtime.h>
#include <hip/hip_bf16.h>

// MultiHeadAttentionClassical: B=2, S=2048, E=1024, H=16, DK=64
// Established: float inputs fp32, out fp32; bf16 internal compute.
// R21: non-attn overhead attack (attn declared local floor at ~72us after
// 6 structurally-distinct attempts all landed 71.6-73.2; R20 proved FETCH
// 74->29MB with zero time delta => not latency-bound).
//  - detect merged into cvt_all (6 -> 5 launches).
//  - cvt_all 4096 -> 512 blocks (grid-stride x8); pack_mask 1024 -> 512
//    (x2). Total blocks 6913 -> 2817 (dispatch-ramp hypothesis).
//  - XCD-chunked bijective swizzles on both GEMMs: qkv w=(bid&7)*96+bid/8
//    (3 W-panels=768KB L2-resident per XCD); out w=(bid&7)*64+bid/8.
//  - attn_kernel carried verbatim from R20 (passed, counters known).

typedef __attribute__((ext_vector_type(8))) short short8;
typedef __attribute__((ext_vector_type(4))) float f32x4;
typedef __attribute__((ext_vector_type(16))) float f32x16;

#define MFMA16(a, b, c) __builtin_amdgcn_mfma_f32_16x16x32_bf16(a, b, c, 0, 0, 0)
#define MFMA32(a, b, c) __builtin_amdgcn_mfma_f32_32x32x16_bf16(a, b, c, 0, 0, 0)

#define BATCH 2
#define SEQ   2048
#define EMB   1024
#define HEADS 16
#define DKK   64

typedef __hip_bfloat16 bf16;

static __device__ __forceinline__ short bf16b(float f) {
    union { bf16 h; short s; } u;
    u.h = __float2bfloat16(f);
    return u.s;
}
static __device__ __forceinline__ unsigned cvtpk(float lo, float hi) {
    unsigned r;
    asm("v_cvt_pk_bf16_f32 %0, %1, %2" : "=v"(r) : "v"(lo), "v"(hi));
    return r;
}
static __device__ __forceinline__ void swap32(unsigned &a, unsigned &b) {
    asm("v_permlane32_swap_b32 %0, %1" : "+v"(a), "+v"(b));
}
static __device__ __forceinline__ short8 ld8k(const bf16* p) {
    return *(const short8*)p;
}
static __device__ __forceinline__ short8 ld8kf(const float* p) {
    const f32x4 a = *(const f32x4*)p;
    const f32x4 b = *(const f32x4*)(p + 4);
    short8 r;
    r[0] = bf16b(a[0]); r[1] = bf16b(a[1]); r[2] = bf16b(a[2]); r[3] = bf16b(a[3]);
    r[4] = bf16b(b[0]); r[5] = bf16b(b[1]); r[6] = bf16b(b[2]); r[7] = bf16b(b[3]);
    return r;
}

// async global->LDS, 16B/lane (LDS dest = wave-uniform base + lane*16)
static __device__ __forceinline__ void glds16(const bf16* g, bf16* l) {
    __builtin_amdgcn_global_load_lds(
        (const __attribute__((address_space(1))) void*)g,
        (__attribute__((address_space(3))) void*)l, 16, 0, 0);
}

// ---------------------------------------------------------------------------
// Fused fp32->bf16 conversion of x, Wq, Wk, Wv, Wo (blocks 0..511, x8
// grid-stride) + mask-dtype detect (block 512): flags[1]=1 -> byte mask.
__global__ __launch_bounds__(256) void cvt_all_det(
        const float* __restrict__ x,  const float* __restrict__ wq,
        const float* __restrict__ wk, const float* __restrict__ wv,
        const float* __restrict__ wo,
        bf16* __restrict__ xb,  bf16* __restrict__ wqb,
        bf16* __restrict__ wkb, bf16* __restrict__ wvb,
        bf16* __restrict__ wob,
        const unsigned int* __restrict__ mw, int* __restrict__ flags) {
    __shared__ int mbyte;
    if (blockIdx.x == 512) {            // detect (runtime probe, R19 lesson)
        if (threadIdx.x == 0) mbyte = 0;
        __syncthreads();
        int mb = 0;
        for (int i = threadIdx.x; i < 4096; i += 256)
            if (mw[i] > 1u) mb = 1;
        if (mb) atomicOr(&mbyte, 1);
        __syncthreads();
        if (threadIdx.x == 0) { flags[0] = 1; flags[1] = mbyte; }
        return;
    }
#pragma unroll
    for (int v = 0; v < 8; ++v) {
        const int bid = blockIdx.x + v * 512;   // 0..4095
        const float* s; bf16* d; int base;
        if (bid < 2048)      { s = x;  d = xb;  base = bid; }
        else if (bid < 2560) { s = wq; d = wqb; base = bid - 2048; }
        else if (bid < 3072) { s = wk; d = wkb; base = bid - 2560; }
        else if (bid < 3584) { s = wv; d = wvb; base = bid - 3072; }
        else                 { s = wo; d = wob; base = bid - 3584; }
        const int i = (base * 256 + threadIdx.x) * 8;
        *(short8*)(d + i) = ld8kf(s + i);
    }
}

// ---------------------------------------------------------------------------
// Byte AND-mask Mp (8MB) in the attn lane order. 512 blocks x2 grid-stride.
//   group g = ((b*32+it)*16+qb)*4 + wv;  per lane 8 u32 at Mp[g*512+lane*8]:
//   word k = kb*4 + t*2 + u covers keys it*64 + kb*32 + t*16 + hi*8 + u*4+{0..3}
//   for q = qb*128 + wv*32 + (lane&31), hi = lane>>5.
//   byte r = 0xFF if mask[b][q][key] == 0 (keep), else 0x00.
__global__ __launch_bounds__(256) void pack_mask(
        const void* __restrict__ mp, unsigned* __restrict__ Mp,
        const int* __restrict__ flags) {
    const bool m8 = flags[1] != 0;
#pragma unroll
    for (int v = 0; v < 2; ++v) {
        const int T = (blockIdx.x + v * 512) * 256 + threadIdx.x;
        const int lane = T & 63, g = T >> 6;        // g in [0, 4096)
        const int wvv = g & 3;
        const int qb  = (g >> 2) & 15;
        const int it  = (g >> 6) & 31;
        const int b   = g >> 11;
        const int l32 = lane & 31, hi = lane >> 5;
        const int q = qb * 128 + wvv * 32 + l32;
        const size_t rowb = ((size_t)(b * 2048 + q)) * 2048;

        unsigned out[8];
        if (m8) {
            const unsigned char* p8 = (const unsigned char*)mp;
#pragma unroll
            for (int k = 0; k < 8; ++k) {
                const int kb = k >> 2, tt = (k >> 1) & 1, u = k & 1;
                const int key0 = it * 64 + kb * 32 + tt * 16 + hi * 8 + u * 4;
                const unsigned vv = *(const unsigned*)(p8 + rowb + key0);
                unsigned w = 0;
#pragma unroll
                for (int r = 0; r < 4; ++r)
                    w |= ((((vv >> (8 * r)) & 0xFFu) == 0u) ? 0xFFu : 0u) << (8 * r);
                out[k] = w;
            }
        } else {
            const int* p32 = (const int*)mp;
#pragma unroll
            for (int k = 0; k < 8; ++k) {
                const int kb = k >> 2, tt = (k >> 1) & 1, u = k & 1;
                const int key0 = it * 64 + kb * 32 + tt * 16 + hi * 8 + u * 4;
                const int4 vv = *(const int4*)(p32 + rowb + key0);
                unsigned w = 0;
                w |=  (vv.x == 0) ? 0xFFu : 0u;
                w |= ((vv.y == 0) ? 0xFFu : 0u) << 8;
                w |= ((vv.z == 0) ? 0xFFu : 0u) << 16;
                w |= ((vv.w == 0) ? 0xFFu : 0u) << 24;
                out[k] = w;
            }
        }
        unsigned* dst = Mp + (size_t)g * 512 + lane * 8;
        *(uint4*)dst       = make_uint4(out[0], out[1], out[2], out[3]);
        *(uint4*)(dst + 4) = make_uint4(out[4], out[5], out[6], out[7]);
    }
}

// ---------------------------------------------------------------------------
// Staged QKV GEMM: C[4096,3072] = X @ [Wq;Wk;Wv]^T + b. 128x128 tile, BK=32,
// 1-barrier double-buffered staging. Q,K -> [b,h,s,d]; V -> [b,h,d,s].
// Q (sel==0) is pre-scaled by 0.125/ln2 so attn can use raw exp2.
// XCD-chunked: w = (bid&7)*96 + bid/8; nb = w/32 (3 W-panels = 768KB
// L2-resident per XCD), mb = w%32 (X streams from L3).
__global__ __launch_bounds__(256) void gemm_qkv_staged(
        const bf16* __restrict__ X,
        const bf16* __restrict__ Wq, const bf16* __restrict__ Wk,
        const bf16* __restrict__ Wv,
        const float* __restrict__ bq, const float* __restrict__ bk,
        const float* __restrict__ bv,
        bf16* __restrict__ qo, bf16* __restrict__ ko, bf16* __restrict__ vo) {
    __shared__ bf16 As[2][128 * 32];   // 2 x 8 KB
    __shared__ bf16 Bs[2][128 * 32];   // 2 x 8 KB

    const int t = threadIdx.x, lane = t & 63;
    const int wv = t >> 6;
    const int bid = blockIdx.x;
    const int w  = ((bid & 7) * 96) + (bid >> 3);   // bijective on [0,768)
    const int nb = w >> 5;              // 0..23
    const int mb = w & 31;              // 0..31
    const int m0 = mb * 128;
    const int n0g = nb * 128;
    const int sel = n0g >> 10;          // 0=Q 1=K 2=V
    const int n0 = n0g & 1023;
    const bf16* W     = sel == 0 ? Wq : (sel == 1 ? Wk : Wv);
    const float* bias = sel == 0 ? bq : (sel == 1 ? bk : bv);
    bf16* out         = sel == 0 ? qo : (sel == 1 ? ko : vo);
    const float oscale = sel == 0 ? 0.18033688011f : 1.0f;   // 0.125/ln2

    const int wr = wv >> 1, wc = wv & 1;
    const int m_off = wr * 64, n_off = wc * 64;
    const int l16 = lane & 15, quad = lane >> 4;

    int srow[2], sg[2];
#pragma unroll
    for (int i = 0; i < 2; ++i) {
        const int c = i * 256 + t;
        srow[i] = c >> 2;
        sg[i]   = (c & 3) ^ (srow[i] & 3);
    }

    f32x4 acc[4][4];
#pragma unroll
    for (int i = 0; i < 4; ++i)
#pragma unroll
        for (int j = 0; j < 4; ++j)
            acc[i][j] = (f32x4){0.f, 0.f, 0.f, 0.f};

    // prologue: stage tile 0 into buf 0
#pragma unroll
    for (int i = 0; i < 2; ++i) {
        glds16(X + (m0 + srow[i]) * 1024 + sg[i] * 8, &As[0][(i * 256 + t) * 8]);
        glds16(W + (n0 + srow[i]) * 1024 + sg[i] * 8, &Bs[0][(i * 256 + t) * 8]);
    }

    for (int it = 0; it < 32; ++it) {
        __syncthreads();
        if (it < 31) {
            const int ktn = (it + 1) * 32;
            const int nb_ = (it + 1) & 1;
#pragma unroll
            for (int i = 0; i < 2; ++i) {
                glds16(X + (m0 + srow[i]) * 1024 + ktn + sg[i] * 8,
                       &As[nb_][(i * 256 + t) * 8]);
                glds16(W + (n0 + srow[i]) * 1024 + ktn + sg[i] * 8,
                       &Bs[nb_][(i * 256 + t) * 8]);
            }
        }
        const bf16* Ab = As[it & 1];
        const bf16* Bb = Bs[it & 1];
        short8 af[4], bfr[4];
#pragma unroll
        for (int ii = 0; ii < 4; ++ii) {
            const int row = m_off + ii * 16 + l16;
            const int slot = quad ^ (row & 3);
            af[ii] = *(const short8*)(Ab + row * 32 + slot * 8);
        }
#pragma unroll
        for (int jj = 0; jj < 4; ++jj) {
            const int row = n_off + jj * 16 + l16;
            const int slot = quad ^ (row & 3);
            bfr[jj] = *(const short8*)(Bb + row * 32 + slot * 8);
        }
#pragma unroll
        for (int ii = 0; ii < 4; ++ii)
#pragma unroll
            for (int jj = 0; jj < 4; ++jj)
                acc[ii][jj] = MFMA16(af[ii], bfr[jj], acc[ii][jj]);
    }

#pragma unroll
    for (int j = 0; j < 4; ++j) {
        const int nl = n0 + n_off + j * 16 + l16;
        const float bj = bias[nl];
        const int h = nl >> 6, d = nl & 63;
#pragma unroll
        for (int i = 0; i < 4; ++i) {
#pragma unroll
            for (int r = 0; r < 4; ++r) {
                const int m = m0 + m_off + i * 16 + quad * 4 + r;
                const float v = (acc[i][j][r] + bj) * oscale;
                const int bb = m >> 11, ss = m & 2047;
                const int idx = (sel == 2)
                    ? ((bb * HEADS + h) * DKK + d) * SEQ + ss
                    : ((bb * HEADS + h) * SEQ + ss) * DKK + d;
                out[idx] = __float2bfloat16(v);
            }
        }
    }
}

// ---------------------------------------------------------------------------
// Staged output GEMM: C[4096,1024] = X @ Wo^T + bo (fp32 out). 128x64 tile,
// BK=32, 1-barrier double-buffered -> 512 blocks (2/CU).
// XCD-chunked: w = (bid&7)*64 + bid/8; nb = w/32, mb = w%32.
__global__ __launch_bounds__(256) void gemm_out_staged(
        const bf16* __restrict__ X,
        const bf16* __restrict__ W, const float* __restrict__ bias,
        float* __restrict__ out) {
    __shared__ bf16 As[2][128 * 32];   // 2 x 8 KB
    __shared__ bf16 Bs[2][64 * 32];    // 2 x 4 KB

    const int t = threadIdx.x, lane = t & 63;
    const int wv = t >> 6;
    const int bid = blockIdx.x;
    const int w  = ((bid & 7) * 64) + (bid >> 3);   // bijective on [0,512)
    const int nb = w >> 5;              // 0..15
    const int mb = w & 31;              // 0..31
    const int m0 = mb * 128, n0 = nb * 64;
    const int wr = wv >> 1, wc = wv & 1;
    const int m_off = wr * 64, n_off = wc * 32;
    const int l16 = lane & 15, quad = lane >> 4;

    int srow[2], sg[2];
#pragma unroll
    for (int i = 0; i < 2; ++i) {
        const int c = i * 256 + t;
        srow[i] = c >> 2;
        sg[i]   = (c & 3) ^ (srow[i] & 3);
    }
    const int brow = t >> 2;
    const int bslot = (t & 3) ^ (brow & 3);

    f32x4 acc[4][2];
#pragma unroll
    for (int i = 0; i < 4; ++i)
#pragma unroll
        for (int j = 0; j < 2; ++j)
            acc[i][j] = (f32x4){0.f, 0.f, 0.f, 0.f};

#pragma unroll
    for (int i = 0; i < 2; ++i)
        glds16(X + (m0 + srow[i]) * 1024 + sg[i] * 8, &As[0][(i * 256 + t) * 8]);
    glds16(W + (n0 + brow) * 1024 + bslot * 8, &Bs[0][t * 8]);

    for (int it = 0; it < 32; ++it) {
        __syncthreads();
        if (it < 31) {
            const int ktn = (it + 1) * 32;
            const int nb_ = (it + 1) & 1;
#pragma unroll
            for (int i = 0; i < 2; ++i)
                glds16(X + (m0 + srow[i]) * 1024 + ktn + sg[i] * 8,
                       &As[nb_][(i * 256 + t) * 8]);
            glds16(W + (n0 + brow) * 1024 + ktn + bslot * 8, &Bs[nb_][t * 8]);
        }
        const bf16* Ab = As[it & 1];
        const bf16* Bb = Bs[it & 1];
        short8 af[4], bfr[2];
#pragma unroll
        for (int ii = 0; ii < 4; ++ii) {
            const int row = m_off + ii * 16 + l16;
            const int slot = quad ^ (row & 3);
            af[ii] = *(const short8*)(Ab + row * 32 + slot * 8);
        }
#pragma unroll
        for (int jj = 0; jj < 2; ++jj) {
            const int row = n_off + jj * 16 + l16;
            const int slot = quad ^ (row & 3);
            bfr[jj] = *(const short8*)(Bb + row * 32 + slot * 8);
        }
#pragma unroll
        for (int ii = 0; ii < 4; ++ii)
#pragma unroll
            for (int jj = 0; jj < 2; ++jj)
                acc[ii][jj] = MFMA16(af[ii], bfr[jj], acc[ii][jj]);
    }

#pragma unroll
    for (int j = 0; j < 2; ++j) {
        const int n = n0 + n_off + j * 16 + l16;
        const float bj = bias[n];
#pragma unroll
        for (int i = 0; i < 4; ++i) {
#pragma unroll
            for (int r = 0; r < 4; ++r) {
                const int m = m0 + m_off + i * 16 + quad * 4 + r;
                out[m * 1024 + n] = acc[i][j][r] + bj;
            }
        }
    }
}

// ---------------------------------------------------------------------------
// Flash attention, 32x32-MFMA in-register-P + counted-vmcnt pipeline
// (verbatim from R20): 1-D grid 512, XCD-swizzled; 4 waves x 32 q-rows;
// triple-buffered K/V, 2-deep prefetch, vmcnt(6) + raw s_barrier.
__global__ __launch_bounds__(256, 2) void attn_kernel(
        const bf16* __restrict__ Qw,
        const bf16* __restrict__ Kw,
        const bf16* __restrict__ Vw,
        const unsigned* __restrict__ Mp,
        bf16* __restrict__ attn_out) {
    const int t = threadIdx.x;
    const int lane = t & 63;
    const int wv   = t >> 6;                // 0..3
    const int l32 = lane & 31, hi = lane >> 5;
    const int bid = blockIdx.x;             // 0..511
    const int w   = ((bid & 7) << 6) | (bid >> 3);   // XCD-chunked work id
    const int qb  = w & 15;
    const int bh  = w >> 4;                 // 0..31 == b*HEADS+h
    const int b   = bh >> 4;
    const int qb0 = qb * 128;

    const bf16* Q  = Qw + bh * SEQ * DKK;
    const bf16* Kp = Kw + bh * SEQ * DKK;
    const bf16* Vt = Vw + bh * DKK * SEQ;

    __shared__ bf16 Ks[3][4096];   // [buf][key*64 + slot*8], slot = s ^ (key&7)
    __shared__ bf16 Vs[3][4096];   // [buf][d*64   + slot*8], slot = s ^ (d&7)

    // Q B-fragments (col q = l32): k-slice ks -> d = ks*16 + hi*8 + e
    short8 qf[4];
#pragma unroll
    for (int ks = 0; ks < 4; ++ks)
        qf[ks] = ld8k(Q + (qb0 + wv * 32 + l32) * DKK + ks * 16 + hi * 8);

    const short ob = bf16b(1.0f);
    short8 ones;
#pragma unroll
    for (int e = 0; e < 8; ++e) ones[e] = ob;

    f32x16 oA = {}, oB = {}, lacc = {};
    const f32x16 z16 = {};

    // staging: two 16B glds16 per thread per array (8KB tiles, 4 loads/thread)
    int srow[2], sg[2];
#pragma unroll
    for (int i = 0; i < 2; ++i) {
        const int c = i * 256 + t;
        srow[i] = c >> 3;
        sg[i]   = (c & 7) ^ (srow[i] & 7);
    }

#define STAGE_TILE(ktn, bufi)                                                  \
    do {                                                                       \
        _Pragma("unroll")                                                      \
        for (int i_ = 0; i_ < 2; ++i_)                                         \
            glds16(Kp + ((ktn) + srow[i_]) * DKK + sg[i_] * 8,                 \
                   &Ks[bufi][(i_ * 256 + t) * 8]);                             \
        _Pragma("unroll")                                                      \
        for (int i_ = 0; i_ < 2; ++i_)                                         \
            glds16(Vt + srow[i_] * SEQ + (ktn) + sg[i_] * 8,                   \
                   &Vs[bufi][(i_ * 256 + t) * 8]);                             \
    } while (0)

    // mask: 8 u32/lane/iter, group = ((b*32+it)*16+qb)*4 + wv
    const unsigned* mp_it =
        Mp + ((size_t)((b * 32) * 16 + qb) * 4 + wv) * 512 + lane * 8;

    // prologue: t0 (4 loads), mask0 (2 loads), t1 (4 loads)
    STAGE_TILE(0, 0);
    uint4 mcA = *(const uint4*)mp_it;
    uint4 mcB = *(const uint4*)(mp_it + 4);
    mp_it += 32768;
    STAGE_TILE(64, 1);

    for (int it = 0; it < 32; ++it) {
        // steady-state outstanding at top: t_it(4) + mask_it(2) + t_{it+1}(4)
        // vmcnt(6) completes exactly t_it. Last iter: drain.
        if (it < 31) asm volatile("s_waitcnt vmcnt(6)" ::: "memory");
        else         asm volatile("s_waitcnt vmcnt(0)" ::: "memory");
        __builtin_amdgcn_s_barrier();
        __builtin_amdgcn_sched_barrier(0);

        uint4 mnA, mnB;
        if (it < 31) {
            mnA = *(const uint4*)mp_it;
            mnB = *(const uint4*)(mp_it + 4);
            mp_it += 32768;
        }
        if (it < 30) STAGE_TILE((it + 2) * 64, (it + 2) % 3);

        const bf16* Kb = Ks[it % 3];
        const bf16* Vb = Vs[it % 3];

        // K A-fragments: rows = keys kb*32 + l32; k(d) = ks*16 + hi*8 + e
        short8 kf0[4], kf1[4];
#pragma unroll
        for (int ks = 0; ks < 4; ++ks) {
            const int sl = (((ks * 2 + hi) ^ (l32 & 7))) * 8;
            kf0[ks] = *(const short8*)(Kb + l32 * 64 + sl);
            kf1[ks] = *(const short8*)(Kb + (32 + l32) * 64 + sl);
        }

        f32x16 s0, s1;
        __builtin_amdgcn_s_setprio(1);
        s0 = MFMA32(kf0[0], qf[0], z16);
        s0 = MFMA32(kf0[1], qf[1], s0);
        s0 = MFMA32(kf0[2], qf[2], s0);
        s0 = MFMA32(kf0[3], qf[3], s0);
        s1 = MFMA32(kf1[0], qf[0], z16);
        s1 = MFMA32(kf1[1], qf[1], s1);
        s1 = MFMA32(kf1[2], qf[2], s1);
        s1 = MFMA32(kf1[3], qf[3], s1);
        __builtin_amdgcn_s_setprio(0);

        // ---- key-block 0 (keys 0..31): softmax in-register + PV ----
        {
            unsigned c0 = cvtpk(__builtin_exp2f(s0[0]),  __builtin_exp2f(s0[1]));
            unsigned c1 = cvtpk(__builtin_exp2f(s0[2]),  __builtin_exp2f(s0[3]));
            unsigned c2 = cvtpk(__builtin_exp2f(s0[4]),  __builtin_exp2f(s0[5]));
            unsigned c3 = cvtpk(__builtin_exp2f(s0[6]),  __builtin_exp2f(s0[7]));
            unsigned c4 = cvtpk(__builtin_exp2f(s0[8]),  __builtin_exp2f(s0[9]));
            unsigned c5 = cvtpk(__builtin_exp2f(s0[10]), __builtin_exp2f(s0[11]));
            unsigned c6 = cvtpk(__builtin_exp2f(s0[12]), __builtin_exp2f(s0[13]));
            unsigned c7 = cvtpk(__builtin_exp2f(s0[14]), __builtin_exp2f(s0[15]));
            swap32(c0, c2); swap32(c1, c3); swap32(c4, c6); swap32(c5, c7);
            union { short8 v; unsigned w[4]; } p0, p1;
            p0.w[0] = c0 & __builtin_amdgcn_perm(0u, mcA.x, 0x01010000u);
            p0.w[1] = c1 & __builtin_amdgcn_perm(0u, mcA.x, 0x03030202u);
            p0.w[2] = c2 & __builtin_amdgcn_perm(0u, mcA.y, 0x01010000u);
            p0.w[3] = c3 & __builtin_amdgcn_perm(0u, mcA.y, 0x03030202u);
            p1.w[0] = c4 & __builtin_amdgcn_perm(0u, mcA.z, 0x01010000u);
            p1.w[1] = c5 & __builtin_amdgcn_perm(0u, mcA.z, 0x03030202u);
            p1.w[2] = c6 & __builtin_amdgcn_perm(0u, mcA.w, 0x01010000u);
            p1.w[3] = c7 & __builtin_amdgcn_perm(0u, mcA.w, 0x03030202u);

            const int sl0 = ((0 + hi) ^ (l32 & 7)) * 8;   // kb=0, t=0
            const int sl1 = ((2 + hi) ^ (l32 & 7)) * 8;   // kb=0, t=1
            const short8 vf00 = *(const short8*)(Vb + l32 * 64 + sl0);
            const short8 vf10 = *(const short8*)(Vb + (32 + l32) * 64 + sl0);
            const short8 vf01 = *(const short8*)(Vb + l32 * 64 + sl1);
            const short8 vf11 = *(const short8*)(Vb + (32 + l32) * 64 + sl1);
            __builtin_amdgcn_s_setprio(1);
            lacc = MFMA32(p0.v, ones, lacc);
            oA = MFMA32(p0.v, vf00, oA);
            oB = MFMA32(p0.v, vf10, oB);
            lacc = MFMA32(p1.v, ones, lacc);
            oA = MFMA32(p1.v, vf01, oA);
            oB = MFMA32(p1.v, vf11, oB);
            __builtin_amdgcn_s_setprio(0);
        }
        // ---- key-block 1 (keys 32..63) ----
        {
            unsigned c0 = cvtpk(__builtin_exp2f(s1[0]),  __builtin_exp2f(s1[1]));
            unsigned c1 = cvtpk(__builtin_exp2f(s1[2]),  __builtin_exp2f(s1[3]));
            unsigned c2 = cvtpk(__builtin_exp2f(s1[4]),  __builtin_exp2f(s1[5]));
            unsigned c3 = cvtpk(__builtin_exp2f(s1[6]),  __builtin_exp2f(s1[7]));
            unsigned c4 = cvtpk(__builtin_exp2f(s1[8]),  __builtin_exp2f(s1[9]));
            unsigned c5 = cvtpk(__builtin_exp2f(s1[10]), __builtin_exp2f(s1[11]));
            unsigned c6 = cvtpk(__builtin_exp2f(s1[12]), __builtin_exp2f(s1[13]));
            unsigned c7 = cvtpk(__builtin_exp2f(s1[14]), __builtin_exp2f(s1[15]));
            swap32(c0, c2); swap32(c1, c3); swap32(c4, c6); swap32(c5, c7);
            union { short8 v; unsigned w[4]; } p0, p1;
            p0.w[0] = c0 & __builtin_amdgcn_perm(0u, mcB.x, 0x01010000u);
            p0.w[1] = c1 & __builtin_amdgcn_perm(0u, mcB.x, 0x03030202u);
            p0.w[2] = c2 & __builtin_amdgcn_perm(0u, mcB.y, 0x01010000u);
            p0.w[3] = c3 & __builtin_amdgcn_perm(0u, mcB.y, 0x03030202u);
            p1.w[0] = c4 & __builtin_amdgcn_perm(0u, mcB.z, 0x01010000u);
            p1.w[1] = c5 & __builtin_amdgcn_perm(0u, mcB.z, 0x03030202u);
            p1.w[2] = c6 & __builtin_amdgcn_perm(0u, mcB.w, 0x01010000u);
            p1.w[3] = c7 & __builtin_amdgcn_perm(0u, mcB.w, 0x03030202u);

            const int sl0 = ((4 + hi) ^ (l32 & 7)) * 8;   // kb=1, t=0
            const int sl1 = ((6 + hi) ^ (l32 & 7)) * 8;   // kb=1, t=1
            const short8 vf00 = *(const short8*)(Vb + l32 * 64 + sl0);
            const short8 vf10 = *(const short8*)(Vb + (32 + l32) * 64 + sl0);
            const short8 vf01 = *(const short8*)(Vb + l32 * 64 + sl1);
            const short8 vf11 = *(const short8*)(Vb + (32 + l32) * 64 + sl1);
            __builtin_amdgcn_s_setprio(1);
            lacc = MFMA32(p0.v, ones, lacc);
            oA = MFMA32(p0.v, vf00, oA);
            oB = MFMA32(p0.v, vf10, oB);
            lacc = MFMA32(p1.v, ones, lacc);
            oA = MFMA32(p1.v, vf01, oA);
            oB = MFMA32(p1.v, vf11, oB);
            __builtin_amdgcn_s_setprio(0);
        }
        if (it < 31) { mcA = mnA; mcB = mnB; }
    }
#undef STAGE_TILE

    // epilogue: lacc[r] = lsum for q-row (r&3)+8*(r>>2)+4*hi (same as o rows)
#pragma unroll
    for (int r = 0; r < 16; ++r) {
        const int qrow = (r & 3) + 8 * (r >> 2) + 4 * hi;
        const float inv = 1.0f / lacc[r];
        const int q = qb0 + wv * 32 + qrow;
        bf16* orow = attn_out + (b * SEQ + q) * EMB + (bh & 15) * DKK;
        orow[l32]      = __float2bfloat16(oA[r] * inv);
        orow[32 + l32] = __float2bfloat16(oB[r] * inv);
    }
}

// ---------------------------------------------------------------------------
extern "C" void kernel_launch(void* const* d_in, const int* in_sizes, int n_in,
                              void* d_out, int out_size, void* d_ws, size_t ws_size,
                              hipStream_t stream) {
    char* ws = (char*)d_ws;
    const size_t MB = 1024 * 1024;
    int*      flags = (int*)ws;
    bf16*     wob   = (bf16*)(ws + 256);                 // [cvt -> out], 2MB
    bf16*     wqb   = (bf16*)(ws + 256 + 2 * MB);        // [cvt -> qkv]
    bf16*     wkb   = (bf16*)(ws + 256 + 4 * MB);
    bf16*     wvb   = (bf16*)(ws + 256 + 6 * MB);
    unsigned* Mp    = (unsigned*)(ws + 256 + 2 * MB);    // [pack -> attn], 8MB,
                                                         // aliases wqb..wvb+pad
    bf16*     xb    = (bf16*)(ws + 256 + 10 * MB);       // [cvt -> qkv], 8MB
    bf16*     k_ws  = (bf16*)(ws + 256 + 18 * MB);       // [qkv -> attn], 8MB
    bf16*     attn_ws = xb;                              // xb dead after QKV

    bf16* q_ws = (bf16*)d_out;
    bf16* v_ws = (bf16*)d_out + 4194304;

    cvt_all_det<<<513, 256, 0, stream>>>(
        (const float*)d_in[0], (const float*)d_in[2], (const float*)d_in[4],
        (const float*)d_in[6], (const float*)d_in[8],
        xb, wqb, wkb, wvb, wob,
        (const unsigned int*)d_in[1], flags);

    gemm_qkv_staged<<<768, 256, 0, stream>>>(
        xb, wqb, wkb, wvb,
        (const float*)d_in[3], (const float*)d_in[5], (const float*)d_in[7],
        q_ws, k_ws, v_ws);

    // after qkv: wqb/wkb/wvb dead -> Mp may alias them
    pack_mask<<<512, 256, 0, stream>>>(d_in[1], Mp, flags);

    attn_kernel<<<512, 256, 0, stream>>>(q_ws, k_ws, v_ws, Mp, attn_ws);

    gemm_out_staged<<<512, 256, 0, stream>>>(
        attn_ws, wob, (const float*)d_in[9], (float*)d_out);
}

// Round 11
// 245.513 us; speedup vs baseline: 1.0539x; 1.0539x over previous
//
#include <hip/hip_runtime.h>
#include <hip/hip_bf16.h>

// MultiHeadAttentionClassical: B=2, S=2048, E=1024, H=16, DK=64
// Established: float inputs fp32, out fp32; bf16 internal compute.
// R22: restore of the session-best R13 configuration (247.1us measured):
//  - cvt_all 4096 blocks, pack_mask 2048 blocks, GEMMs unswizzled,
//    attn = 8 waves x 16 q-rows, 512 thr, grid 512 (2 blocks/CU),
//    post-exp2 byte-AND mask via v_perm, ones-MFMA lsum, setprio.
//  - ONE change: detect_kernel folded into pack_mask as a per-block
//    self-detect (same 4096-word runtime probe, now from L2) -> 5 launches.
// R21 post-mortem: launch-count & GEMM-swizzle hypotheses both refuted
// (258.8us, +7.6 regression); R20 proved attn FETCH 74->29MB with zero
// time delta. attn is at a structural floor (~72us) after 6 distinct
// structures; non-attn floor ~176us with this decomposition.

typedef __attribute__((ext_vector_type(8))) short short8;
typedef __attribute__((ext_vector_type(4))) short s16x4;
typedef __attribute__((ext_vector_type(4))) float f32x4;
typedef __attribute__((ext_vector_type(2))) unsigned uint32x2;

#define MFMA16(a, b, c) __builtin_amdgcn_mfma_f32_16x16x32_bf16(a, b, c, 0, 0, 0)

#define BATCH 2
#define SEQ   2048
#define EMB   1024
#define HEADS 16
#define DKK   64

typedef __hip_bfloat16 bf16;
typedef unsigned long long u64;

static __device__ __forceinline__ short bf16b(float f) {
    union { bf16 h; short s; } u;
    u.h = __float2bfloat16(f);
    return u.s;
}
static __device__ __forceinline__ short8 ld8k(const bf16* p) {
    return *(const short8*)p;
}
static __device__ __forceinline__ short8 ld8kf(const float* p) {
    const f32x4 a = *(const f32x4*)p;
    const f32x4 b = *(const f32x4*)(p + 4);
    short8 r;
    r[0] = bf16b(a[0]); r[1] = bf16b(a[1]); r[2] = bf16b(a[2]); r[3] = bf16b(a[3]);
    r[4] = bf16b(b[0]); r[5] = bf16b(b[1]); r[6] = bf16b(b[2]); r[7] = bf16b(b[3]);
    return r;
}

// async global->LDS, 16B/lane (LDS dest = wave-uniform base + lane*16)
static __device__ __forceinline__ void glds16(const bf16* g, bf16* l) {
    __builtin_amdgcn_global_load_lds(
        (const __attribute__((address_space(1))) void*)g,
        (__attribute__((address_space(3))) void*)l, 16, 0, 0);
}

// ---------------------------------------------------------------------------
// Build byte AND-mask Mp (8MB) in attn lane order. Mask dtype self-detected
// per block (runtime probe -- R19 proved it is not statically decidable):
// scan first 4096 u32 words; any word >1 => byte mask (4 bools packed).
//   word index w = ((((b*32+it)*16+qb)*8+wv)*4 + j)*64 + lane
//   byte r of word = 0xFF if mask[b][q][it*64 + j*16 + quad*4 + r] == 0
//   where q = qb*128 + wv*16 + (lane&15), quad = lane>>4.
__global__ __launch_bounds__(256) void pack_mask(
        const void* __restrict__ mp, unsigned* __restrict__ Mp) {
    __shared__ int s_m8;
    if (threadIdx.x == 0) s_m8 = 0;
    __syncthreads();
    {
        const unsigned* mw = (const unsigned*)mp;
        int mb = 0;
        for (int i = threadIdx.x; i < 4096; i += 256)
            if (mw[i] > 1u) mb = 1;
        if (mb) atomicOr(&s_m8, 1);
    }
    __syncthreads();
    const bool m8 = s_m8 != 0;

    const int T = blockIdx.x * 256 + threadIdx.x;      // 524288 threads
    const int lane = T & 63, rest = T >> 6;            // rest in [0, 8192)
    const int wvv = rest & 7;
    const int qb  = (rest >> 3) & 15;
    const int it  = (rest >> 7) & 31;
    const int b   = rest >> 12;
    const int l16 = lane & 15, quad = lane >> 4;
    const int q = qb * 128 + wvv * 16 + l16;
    const size_t rowb = ((size_t)(b * 2048 + q)) * 2048;
    const int k0 = it * 64 + quad * 4;

    unsigned out[4];
    if (m8) {
        const unsigned char* p8 = (const unsigned char*)mp;
#pragma unroll
        for (int j = 0; j < 4; ++j) {
            const unsigned v = *(const unsigned*)(p8 + rowb + k0 + j * 16);
            unsigned w = 0;
#pragma unroll
            for (int r = 0; r < 4; ++r)
                w |= ((((v >> (8 * r)) & 0xFFu) == 0u) ? 0xFFu : 0u) << (8 * r);
            out[j] = w;
        }
    } else {
        const int* p32 = (const int*)mp;
#pragma unroll
        for (int j = 0; j < 4; ++j) {
            const int4 v = *(const int4*)(p32 + rowb + k0 + j * 16);
            unsigned w = 0;
            w |=  (v.x == 0) ? 0xFFu : 0u;
            w |= ((v.y == 0) ? 0xFFu : 0u) << 8;
            w |= ((v.z == 0) ? 0xFFu : 0u) << 16;
            w |= ((v.w == 0) ? 0xFFu : 0u) << 24;
            out[j] = w;
        }
    }
    unsigned* dst = Mp + (size_t)rest * 256 + lane;
#pragma unroll
    for (int j = 0; j < 4; ++j) dst[j * 64] = out[j];
}

// ---------------------------------------------------------------------------
// Fused fp32->bf16 conversion of x, Wq, Wk, Wv, Wo.
__global__ __launch_bounds__(256) void cvt_all(
        const float* __restrict__ x,  const float* __restrict__ wq,
        const float* __restrict__ wk, const float* __restrict__ wv,
        const float* __restrict__ wo,
        bf16* __restrict__ xb,  bf16* __restrict__ wqb,
        bf16* __restrict__ wkb, bf16* __restrict__ wvb,
        bf16* __restrict__ wob) {
    const int bid = blockIdx.x;
    const float* s; bf16* d; int base;
    if (bid < 2048)      { s = x;  d = xb;  base = bid; }
    else if (bid < 2560) { s = wq; d = wqb; base = bid - 2048; }
    else if (bid < 3072) { s = wk; d = wkb; base = bid - 2560; }
    else if (bid < 3584) { s = wv; d = wvb; base = bid - 3072; }
    else                 { s = wo; d = wob; base = bid - 3584; }
    const int i = (base * 256 + threadIdx.x) * 8;
    *(short8*)(d + i) = ld8kf(s + i);
}

// ---------------------------------------------------------------------------
// Staged QKV GEMM: C[4096,3072] = X @ [Wq;Wk;Wv]^T + b. 128x128 tile, BK=32,
// 1-barrier double-buffered staging. Q,K -> [b,h,s,d]; V -> [b,h,d,s].
// Q (sel==0) is pre-scaled by 0.125/ln2 so attn can use raw exp2.
__global__ __launch_bounds__(256) void gemm_qkv_staged(
        const bf16* __restrict__ X,
        const bf16* __restrict__ Wq, const bf16* __restrict__ Wk,
        const bf16* __restrict__ Wv,
        const float* __restrict__ bq, const float* __restrict__ bk,
        const float* __restrict__ bv,
        bf16* __restrict__ qo, bf16* __restrict__ ko, bf16* __restrict__ vo) {
    __shared__ bf16 As[2][128 * 32];   // 2 x 8 KB
    __shared__ bf16 Bs[2][128 * 32];   // 2 x 8 KB

    const int t = threadIdx.x, lane = t & 63;
    const int wv = t >> 6;
    const int mb = blockIdx.x / 24, nb = blockIdx.x % 24;
    const int m0 = mb * 128;
    const int n0g = nb * 128;
    const int sel = n0g >> 10;          // 0=Q 1=K 2=V
    const int n0 = n0g & 1023;
    const bf16* W     = sel == 0 ? Wq : (sel == 1 ? Wk : Wv);
    const float* bias = sel == 0 ? bq : (sel == 1 ? bk : bv);
    bf16* out         = sel == 0 ? qo : (sel == 1 ? ko : vo);
    const float oscale = sel == 0 ? 0.18033688011f : 1.0f;   // 0.125/ln2

    const int wr = wv >> 1, wc = wv & 1;
    const int m_off = wr * 64, n_off = wc * 64;
    const int l16 = lane & 15, quad = lane >> 4;

    int srow[2], sg[2];
#pragma unroll
    for (int i = 0; i < 2; ++i) {
        const int c = i * 256 + t;
        srow[i] = c >> 2;
        sg[i]   = (c & 3) ^ (srow[i] & 3);
    }

    f32x4 acc[4][4];
#pragma unroll
    for (int i = 0; i < 4; ++i)
#pragma unroll
        for (int j = 0; j < 4; ++j)
            acc[i][j] = (f32x4){0.f, 0.f, 0.f, 0.f};

    // prologue: stage tile 0 into buf 0
#pragma unroll
    for (int i = 0; i < 2; ++i) {
        glds16(X + (m0 + srow[i]) * 1024 + sg[i] * 8, &As[0][(i * 256 + t) * 8]);
        glds16(W + (n0 + srow[i]) * 1024 + sg[i] * 8, &Bs[0][(i * 256 + t) * 8]);
    }

    for (int it = 0; it < 32; ++it) {
        __syncthreads();
        if (it < 31) {
            const int ktn = (it + 1) * 32;
            const int nb_ = (it + 1) & 1;
#pragma unroll
            for (int i = 0; i < 2; ++i) {
                glds16(X + (m0 + srow[i]) * 1024 + ktn + sg[i] * 8,
                       &As[nb_][(i * 256 + t) * 8]);
                glds16(W + (n0 + srow[i]) * 1024 + ktn + sg[i] * 8,
                       &Bs[nb_][(i * 256 + t) * 8]);
            }
        }
        const bf16* Ab = As[it & 1];
        const bf16* Bb = Bs[it & 1];
        short8 af[4], bfr[4];
#pragma unroll
        for (int ii = 0; ii < 4; ++ii) {
            const int row = m_off + ii * 16 + l16;
            const int slot = quad ^ (row & 3);
            af[ii] = *(const short8*)(Ab + row * 32 + slot * 8);
        }
#pragma unroll
        for (int jj = 0; jj < 4; ++jj) {
            const int row = n_off + jj * 16 + l16;
            const int slot = quad ^ (row & 3);
            bfr[jj] = *(const short8*)(Bb + row * 32 + slot * 8);
        }
#pragma unroll
        for (int ii = 0; ii < 4; ++ii)
#pragma unroll
            for (int jj = 0; jj < 4; ++jj)
                acc[ii][jj] = MFMA16(af[ii], bfr[jj], acc[ii][jj]);
    }

#pragma unroll
    for (int j = 0; j < 4; ++j) {
        const int nl = n0 + n_off + j * 16 + l16;
        const float bj = bias[nl];
        const int h = nl >> 6, d = nl & 63;
#pragma unroll
        for (int i = 0; i < 4; ++i) {
#pragma unroll
            for (int r = 0; r < 4; ++r) {
                const int m = m0 + m_off + i * 16 + quad * 4 + r;
                const float v = (acc[i][j][r] + bj) * oscale;
                const int bb = m >> 11, ss = m & 2047;
                const int idx = (sel == 2)
                    ? ((bb * HEADS + h) * DKK + d) * SEQ + ss
                    : ((bb * HEADS + h) * SEQ + ss) * DKK + d;
                out[idx] = __float2bfloat16(v);
            }
        }
    }
}

// ---------------------------------------------------------------------------
// Staged output GEMM: C[4096,1024] = X @ Wo^T + bo (fp32 out). 128x64 tile,
// BK=32, 1-barrier double-buffered -> 512 blocks (2/CU).
__global__ __launch_bounds__(256) void gemm_out_staged(
        const bf16* __restrict__ X,
        const bf16* __restrict__ W, const float* __restrict__ bias,
        float* __restrict__ out) {
    __shared__ bf16 As[2][128 * 32];   // 2 x 8 KB
    __shared__ bf16 Bs[2][64 * 32];    // 2 x 4 KB

    const int t = threadIdx.x, lane = t & 63;
    const int wv = t >> 6;
    const int mb = blockIdx.x >> 4, nb = blockIdx.x & 15;
    const int m0 = mb * 128, n0 = nb * 64;
    const int wr = wv >> 1, wc = wv & 1;
    const int m_off = wr * 64, n_off = wc * 32;
    const int l16 = lane & 15, quad = lane >> 4;

    int srow[2], sg[2];
#pragma unroll
    for (int i = 0; i < 2; ++i) {
        const int c = i * 256 + t;
        srow[i] = c >> 2;
        sg[i]   = (c & 3) ^ (srow[i] & 3);
    }
    const int brow = t >> 2;
    const int bslot = (t & 3) ^ (brow & 3);

    f32x4 acc[4][2];
#pragma unroll
    for (int i = 0; i < 4; ++i)
#pragma unroll
        for (int j = 0; j < 2; ++j)
            acc[i][j] = (f32x4){0.f, 0.f, 0.f, 0.f};

#pragma unroll
    for (int i = 0; i < 2; ++i)
        glds16(X + (m0 + srow[i]) * 1024 + sg[i] * 8, &As[0][(i * 256 + t) * 8]);
    glds16(W + (n0 + brow) * 1024 + bslot * 8, &Bs[0][t * 8]);

    for (int it = 0; it < 32; ++it) {
        __syncthreads();
        if (it < 31) {
            const int ktn = (it + 1) * 32;
            const int nb_ = (it + 1) & 1;
#pragma unroll
            for (int i = 0; i < 2; ++i)
                glds16(X + (m0 + srow[i]) * 1024 + ktn + sg[i] * 8,
                       &As[nb_][(i * 256 + t) * 8]);
            glds16(W + (n0 + brow) * 1024 + ktn + bslot * 8, &Bs[nb_][t * 8]);
        }
        const bf16* Ab = As[it & 1];
        const bf16* Bb = Bs[it & 1];
        short8 af[4], bfr[2];
#pragma unroll
        for (int ii = 0; ii < 4; ++ii) {
            const int row = m_off + ii * 16 + l16;
            const int slot = quad ^ (row & 3);
            af[ii] = *(const short8*)(Ab + row * 32 + slot * 8);
        }
#pragma unroll
        for (int jj = 0; jj < 2; ++jj) {
            const int row = n_off + jj * 16 + l16;
            const int slot = quad ^ (row & 3);
            bfr[jj] = *(const short8*)(Bb + row * 32 + slot * 8);
        }
#pragma unroll
        for (int ii = 0; ii < 4; ++ii)
#pragma unroll
            for (int jj = 0; jj < 2; ++jj)
                acc[ii][jj] = MFMA16(af[ii], bfr[jj], acc[ii][jj]);
    }

#pragma unroll
    for (int j = 0; j < 2; ++j) {
        const int n = n0 + n_off + j * 16 + l16;
        const float bj = bias[n];
#pragma unroll
        for (int i = 0; i < 4; ++i) {
#pragma unroll
            for (int r = 0; r < 4; ++r) {
                const int m = m0 + m_off + i * 16 + quad * 4 + r;
                out[m * 1024 + n] = acc[i][j][r] + bj;
            }
        }
    }
}

// ---------------------------------------------------------------------------
// Flash attention (R13, session-best 71.6us): block = 128 q-rows x one
// (b,h); 8 waves x 16 q-rows (512 threads, grid 512 = 2 blocks/CU).
// K/V double-buffered LDS staging, one barrier/iter.
// QK^T computed TRANSPOSED (A=K, B=Q): C col = q = l16, row = key = quad*4+r.
// lsum via ones-column MFMA (output layout matches o[] -> no epilogue shfl).
// Mask applied post-exp2 on packed bf16 pairs: u32 AND-mask from Mp via
// v_perm byte expansion (no per-score VALU on the exp2 chain).
__global__ __launch_bounds__(512, 4) void attn_kernel(
        const bf16* __restrict__ Qw,
        const bf16* __restrict__ Kw,
        const bf16* __restrict__ Vw,
        const unsigned* __restrict__ Mp,
        bf16* __restrict__ attn_out) {
    const int t = threadIdx.x;
    const int lane = t & 63;
    const int wv   = t >> 6;                // 0..7
    const int l16 = lane & 15, quad = lane >> 4;
    const int h = blockIdx.y, b = blockIdx.z;
    const int bh = b * HEADS + h;
    const int qb = blockIdx.x;
    const int qb0 = qb * 128;

    const bf16* Q  = Qw + bh * SEQ * DKK;
    const bf16* Kp = Kw + bh * SEQ * DKK;
    const bf16* Vt = Vw + bh * DKK * SEQ;

    __shared__ bf16 Ks[2][4096];            // [buf][key*64 + slot*8]
    __shared__ bf16 Vs[2][4096];            // [buf][d*64   + slot*8]
    __shared__ bf16 lds_p[8][16][72];       // [wave][q=l16][key(+pad)]

    // Q fragments for this wave's 16 q-rows (pre-scaled by 0.125/ln2)
    short8 qf[2];
#pragma unroll
    for (int t2 = 0; t2 < 2; ++t2)
        qf[t2] = ld8k(Q + (qb0 + wv * 16 + l16) * DKK + t2 * 32 + quad * 8);

    // ones B-fragment (bf16 1.0) for the row-sum MFMA
    const short ob = bf16b(1.0f);
    short8 ones;
#pragma unroll
    for (int e = 0; e < 8; ++e) ones[e] = ob;

    f32x4 o[4];
#pragma unroll
    for (int jd = 0; jd < 4; ++jd) o[jd] = (f32x4){0.f, 0.f, 0.f, 0.f};
    f32x4 lacc = (f32x4){0.f, 0.f, 0.f, 0.f};
    const f32x4 zacc = (f32x4){0.f, 0.f, 0.f, 0.f};   // persistent zero seed

    // staging: one 16B glds16 per thread per array (512 threads x 16B = 8KB)
    const int srow = t >> 3;                // 0..63
    const int sg   = (t & 7) ^ (srow & 7);

    // prologue: stage tile 0 into buf 0
    glds16(Kp + srow * DKK + sg * 8, &Ks[0][t * 8]);
    glds16(Vt + srow * SEQ + sg * 8, &Vs[0][t * 8]);

    // mask base: word index = (((b*32+it)*16+qb)*8+wv)*4*64 + j*64 + lane
    const size_t mbase = (size_t)(b * 512 + qb) * 2048 + wv * 256 + lane;

    for (int it = 0; it < SEQ / 64; ++it) {
        __syncthreads();
        if (it < SEQ / 64 - 1) {
            const int nb_ = (it + 1) & 1;
            const int ktn = (it + 1) * 64;
            glds16(Kp + (ktn + srow) * DKK + sg * 8, &Ks[nb_][t * 8]);
            glds16(Vt + srow * SEQ + ktn + sg * 8, &Vs[nb_][t * 8]);
        }

        // mask words for this iter (coalesced; L2/L3-resident, head-shared)
        const unsigned* mrow = Mp + mbase + (size_t)it * 32768;
        unsigned m32[4];
#pragma unroll
        for (int j = 0; j < 4; ++j) m32[j] = mrow[j * 64];

        const bf16* Kb = Ks[it & 1];
        const bf16* Vb = Vs[it & 1];

        // K fragments (A-operand: m=key)
        short8 kf[2][4];
#pragma unroll
        for (int t2 = 0; t2 < 2; ++t2)
#pragma unroll
            for (int j = 0; j < 4; ++j) {
                const int row = j * 16 + l16;
                const int slot = (t2 * 4 + quad) ^ (row & 7);
                kf[t2][j] = *(const short8*)(Kb + row * 64 + slot * 8);
            }

        // S^T: s[j] -> D[key = j*16+quad*4+r][q = l16]
        f32x4 s[4];
        __builtin_amdgcn_s_setprio(1);
#pragma unroll
        for (int j = 0; j < 4; ++j) {
            s[j] = MFMA16(kf[0][j], qf[0], zacc);
            s[j] = MFMA16(kf[1][j], qf[1], s[j]);
        }
        __builtin_amdgcn_s_setprio(0);

        // softmax: exp2 directly on MFMA output; mask via AND on packed bf16
#pragma unroll
        for (int j = 0; j < 4; ++j) {
            union { s16x4 v; unsigned w[2]; } pk;
#pragma unroll
            for (int r = 0; r < 4; ++r)
                pk.v[r] = bf16b(__builtin_exp2f(s[j][r]));
            pk.w[0] &= __builtin_amdgcn_perm(0u, m32[j], 0x01010000u);
            pk.w[1] &= __builtin_amdgcn_perm(0u, m32[j], 0x03030202u);
            *(s16x4*)(&lds_p[wv][l16][j * 16 + quad * 4]) = pk.v;
        }

        // PV (A = P: m=q, k=key; B = V^T: n=d) + row-sum via ones-MFMA
        __builtin_amdgcn_s_setprio(1);
#pragma unroll
        for (int t2 = 0; t2 < 2; ++t2) {
            short8 vf[4];
#pragma unroll
            for (int jd = 0; jd < 4; ++jd) {
                const int row = jd * 16 + l16;
                const int slot = (t2 * 4 + quad) ^ (row & 7);
                vf[jd] = *(const short8*)(Vb + row * 64 + slot * 8);
            }
            const short8 pf = *(const short8*)(&lds_p[wv][l16][t2 * 32 + quad * 8]);
            lacc = MFMA16(pf, ones, lacc);
#pragma unroll
            for (int jd = 0; jd < 4; ++jd)
                o[jd] = MFMA16(pf, vf[jd], o[jd]);
        }
        __builtin_amdgcn_s_setprio(0);
    }

    // epilogue: lacc[r] = lsum for q = quad*4+r (same row layout as o[])
#pragma unroll
    for (int r = 0; r < 4; ++r) {
        const float inv = 1.0f / lacc[r];
        const int q = qb0 + wv * 16 + quad * 4 + r;
#pragma unroll
        for (int jd = 0; jd < 4; ++jd)
            attn_out[(b * SEQ + q) * EMB + h * DKK + jd * 16 + l16] =
                __float2bfloat16(o[jd][r] * inv);
    }
}

// ---------------------------------------------------------------------------
extern "C" void kernel_launch(void* const* d_in, const int* in_sizes, int n_in,
                              void* d_out, int out_size, void* d_ws, size_t ws_size,
                              hipStream_t stream) {
    char* ws = (char*)d_ws;
    const size_t MB = 1024 * 1024;
    bf16*     wob   = (bf16*)(ws + 256);                 // [cvt -> out], 2MB
    bf16*     wqb   = (bf16*)(ws + 256 + 2 * MB);        // [cvt -> qkv]
    bf16*     wkb   = (bf16*)(ws + 256 + 4 * MB);
    bf16*     wvb   = (bf16*)(ws + 256 + 6 * MB);
    unsigned* Mp    = (unsigned*)(ws + 256 + 2 * MB);    // [pack -> attn], 8MB,
                                                         // aliases wqb..wvb+pad
    bf16*     xb    = (bf16*)(ws + 256 + 10 * MB);       // [cvt -> qkv], 8MB
    bf16*     k_ws  = (bf16*)(ws + 256 + 18 * MB);       // [qkv -> attn], 8MB
    bf16*     attn_ws = xb;                              // xb dead after QKV

    bf16* q_ws = (bf16*)d_out;
    bf16* v_ws = (bf16*)d_out + 4194304;

    cvt_all<<<4096, 256, 0, stream>>>(
        (const float*)d_in[0], (const float*)d_in[2], (const float*)d_in[4],
        (const float*)d_in[6], (const float*)d_in[8],
        xb, wqb, wkb, wvb, wob);

    gemm_qkv_staged<<<768, 256, 0, stream>>>(
        xb, wqb, wkb, wvb,
        (const float*)d_in[3], (const float*)d_in[5], (const float*)d_in[7],
        q_ws, k_ws, v_ws);

    // after qkv: wqb/wkb/wvb dead -> Mp may alias them
    pack_mask<<<2048, 256, 0, stream>>>(d_in[1], Mp);

    attn_kernel<<<dim3(SEQ / 128, HEADS, BATCH), 512, 0, stream>>>(
        q_ws, k_ws, v_ws, Mp, attn_ws);

    gemm_out_staged<<<512, 256, 0, stream>>>(
        attn_ws, wob, (const float*)d_in[9], (float*)d_out);
}